// Round 3
// baseline (644.928 us; speedup 1.0000x reference)
//
#include <hip/hip_runtime.h>

#define RSQRT2 0.70710678118654752f

// ---------------- histograms ----------------

__global__ void k_edge_hist(const int* __restrict__ ei, int E,
                            int* __restrict__ row_cnt, int* __restrict__ col_cnt) {
    int e = blockIdx.x * 256 + threadIdx.x;
    if (e < E) {
        atomicAdd(&row_cnt[ei[e]], 1);        // edge_index[0] = row
        atomicAdd(&col_cnt[ei[E + e]], 1);    // edge_index[1] = col
    }
}

__global__ void k_bc_hist(const int* __restrict__ assign, int N, int* __restrict__ bc_cnt) {
    int i = blockIdx.x * 256 + threadIdx.x;
    if (i < N) atomicAdd(&bc_cnt[assign[i]], 1);
}

__global__ void k_deg(const int* __restrict__ col_cnt, const int* __restrict__ bc_cnt,
                      int N, int M, float* __restrict__ d, float* __restrict__ dcol) {
    int i = blockIdx.x * 256 + threadIdx.x;
    if (i < N) d[i] = rsqrtf(1.0f + (float)col_cnt[i]);
    if (i < M) dcol[i] = rsqrtf(1.0f + (float)bc_cnt[i]);
}

// ---------------- exclusive scan over row_cnt -> row_ptr ----------------

__global__ void k_scanA(const int* __restrict__ cnt, int n,
                        int* __restrict__ out, int* __restrict__ bsums) {
    __shared__ int sm[1024];
    int t = threadIdx.x;
    int gid = blockIdx.x * 1024 + t;
    int v = (gid < n) ? cnt[gid] : 0;
    sm[t] = v;
    __syncthreads();
    for (int off = 1; off < 1024; off <<= 1) {
        int u = (t >= off) ? sm[t - off] : 0;
        __syncthreads();
        sm[t] += u;
        __syncthreads();
    }
    if (gid < n) out[gid] = sm[t] - v;          // exclusive
    if (t == 1023) bsums[blockIdx.x] = sm[1023]; // block total
}

__global__ void k_scanB(int* __restrict__ bsums, int nb) {
    if (threadIdx.x == 0 && blockIdx.x == 0) {
        int run = 0;
        for (int i = 0; i < nb; ++i) { int v = bsums[i]; bsums[i] = run; run += v; }
    }
}

__global__ void k_scanC(int* __restrict__ row_ptr, const int* __restrict__ bsums,
                        int n, int E) {
    int gid = blockIdx.x * 256 + threadIdx.x;
    if (gid < n) row_ptr[gid] += bsums[gid >> 10];
    else if (gid == n) row_ptr[n] = E;
}

// ---------------- bucket edges by row (CSR) ----------------

__global__ void k_bucket(const int* __restrict__ ei, int E,
                         const int* __restrict__ row_ptr, int* __restrict__ row_fill,
                         int* __restrict__ col_sorted) {
    int e = blockIdx.x * 256 + threadIdx.x;
    if (e < E) {
        int r = ei[e];
        int pos = atomicAdd(&row_fill[r], 1);
        col_sorted[row_ptr[r] + pos] = ei[E + e];
    }
}

// ---------------- small GEMMs: ZW = bcf@WZ, ZA = bcf@Walpha (M x 128) ----------------

__global__ void k_bc_gemm(const float* __restrict__ bcf,
                          const float* __restrict__ WZ, const float* __restrict__ WA,
                          float* __restrict__ ZW, float* __restrict__ ZA) {
    __shared__ float row[128];
    int r = blockIdx.x;
    int c = threadIdx.x;
    row[c] = bcf[r * 128 + c];
    __syncthreads();
    float aW = 0.f, aA = 0.f;
#pragma unroll 8
    for (int k = 0; k < 128; ++k) {
        float xv = row[k];
        aW = fmaf(xv, WZ[k * 128 + c], aW);
        aA = fmaf(xv, WA[k * 128 + c], aA);
    }
    ZW[r * 128 + c] = aW;
    ZA[r * 128 + c] = aA;
}

// ---------------- G = x@WX + bhat(ZA) ----------------
// block: 256 threads -> 64 rows x 128 cols tile; thread: 4 rows x 8 cols micro-tile.

#define GB_ROWS 64
#define GB_KC 64

__global__ __launch_bounds__(256) void k_G(
    const float* __restrict__ x, const float* __restrict__ WX,
    const float* __restrict__ ZA, const int* __restrict__ assign,
    const float* __restrict__ dcol, float* __restrict__ G, int N, int M) {
    __shared__ float xs[GB_ROWS][GB_KC + 1];   // +1 pad: 4 distinct rows/wave -> no bank conflict
    __shared__ float ws[GB_KC][128];           // row-contiguous reads -> conflict-free

    int tid = threadIdx.x;
    int tc = tid & 15;    // col group: c0 = tc*8
    int tr = tid >> 4;    // row group: rows tr*4 .. tr*4+3
    int row0 = blockIdx.x * GB_ROWS;
    int c0 = tc * 8;

    float acc[4][8];
#pragma unroll
    for (int r = 0; r < 4; ++r)
#pragma unroll
        for (int j = 0; j < 8; ++j) acc[r][j] = 0.f;

    for (int kc = 0; kc < 128; kc += GB_KC) {
        for (int idx = tid; idx < GB_ROWS * GB_KC; idx += 256) {
            int r = idx >> 6;
            int k = idx & 63;
            int gr = row0 + r;
            xs[r][k] = (gr < N) ? x[gr * 128 + kc + k] : 0.f;
        }
        for (int idx = tid; idx < GB_KC * 128; idx += 256) {
            int k = idx >> 7;
            int c = idx & 127;
            ws[k][c] = WX[(kc + k) * 128 + c];
        }
        __syncthreads();
#pragma unroll 4
        for (int k = 0; k < GB_KC; ++k) {
            float a0 = xs[tr * 4 + 0][k];
            float a1 = xs[tr * 4 + 1][k];
            float a2 = xs[tr * 4 + 2][k];
            float a3 = xs[tr * 4 + 3][k];
            float4 b0 = *(const float4*)&ws[k][c0];
            float4 b1 = *(const float4*)&ws[k][c0 + 4];
            float bv[8] = {b0.x, b0.y, b0.z, b0.w, b1.x, b1.y, b1.z, b1.w};
#pragma unroll
            for (int j = 0; j < 8; ++j) {
                float b = bv[j];
                acc[0][j] = fmaf(a0, b, acc[0][j]);
                acc[1][j] = fmaf(a1, b, acc[1][j]);
                acc[2][j] = fmaf(a2, b, acc[2][j]);
                acc[3][j] = fmaf(a3, b, acc[3][j]);
            }
        }
        __syncthreads();
    }

    // epilogue: G[gr][c] = xWX + drow*(dcol[a]*ZA[a][c] + (gr<M ? dcol[gr]*ZA[gr][c] : 0))
#pragma unroll
    for (int rr = 0; rr < 4; ++rr) {
        int gr = row0 + tr * 4 + rr;
        if (gr >= N) continue;
        int ai = assign[gr];
        float dca = dcol[ai];
        float dr = (gr < M) ? RSQRT2 : 1.0f;
        float dci = (gr < M) ? dcol[gr] : 0.0f;
#pragma unroll
        for (int j = 0; j < 8; ++j) {
            float bh = dca * ZA[ai * 128 + c0 + j];
            if (gr < M) bh = fmaf(dci, ZA[gr * 128 + c0 + j], bh);
            bh *= dr;
            G[gr * 128 + c0 + j] = acc[rr][j] + bh;
        }
    }
}

// ---------------- final: out = (d*(gather + d*G) + Zprime)/3 ----------------
// one wave (64 lanes) per node; lane handles float2 (dims 2l, 2l+1).

__global__ __launch_bounds__(256) void k_final(
    const float* __restrict__ G, const float* __restrict__ d,
    const int* __restrict__ row_ptr, const int* __restrict__ col_sorted,
    const float* __restrict__ ZW, const float* __restrict__ dcol,
    const int* __restrict__ assign, float* __restrict__ out, int N, int M) {
    int wid = threadIdx.x >> 6;
    int lane = threadIdx.x & 63;
    int i = blockIdx.x * 4 + wid;
    if (i >= N) return;

    const float2* G2 = (const float2*)G;
    int s = row_ptr[i];
    int e = row_ptr[i + 1];
    float ax = 0.f, ay = 0.f;
    for (int j = s; j < e; ++j) {
        int c = col_sorted[j];
        float dc = d[c];
        float2 g = G2[c * 64 + lane];
        ax = fmaf(dc, g.x, ax);
        ay = fmaf(dc, g.y, ay);
    }
    float di = d[i];
    float2 gi = G2[i * 64 + lane];
    float ox = di * fmaf(di, gi.x, ax);
    float oy = di * fmaf(di, gi.y, ay);

    int ai = assign[i];
    float dca = dcol[ai];
    const float2* ZW2 = (const float2*)ZW;
    float2 zw = ZW2[ai * 64 + lane];
    float zx = dca * zw.x, zy = dca * zw.y;
    if (i < M) {
        float dci = dcol[i];
        float2 zwi = ZW2[i * 64 + lane];
        zx = fmaf(dci, zwi.x, zx);
        zy = fmaf(dci, zwi.y, zy);
    }
    float dr = (i < M) ? RSQRT2 : 1.0f;

    float2 o;
    o.x = (ox + zx * dr) * (1.0f / 3.0f);
    o.y = (oy + zy * dr) * (1.0f / 3.0f);
    ((float2*)out)[i * 64 + lane] = o;
}

// ---------------- launch ----------------

extern "C" void kernel_launch(void* const* d_in, const int* in_sizes, int n_in,
                              void* d_out, int out_size, void* d_ws, size_t ws_size,
                              hipStream_t stream) {
    const float* x      = (const float*)d_in[0];
    const int*   ei     = (const int*)d_in[1];
    const float* bcf    = (const float*)d_in[2];
    const int*   assign = (const int*)d_in[3];
    const float* WX     = (const float*)d_in[4];
    const float* WZ     = (const float*)d_in[5];
    const float* WA     = (const float*)d_in[6];
    float* out = (float*)d_out;

    const int N = in_sizes[0] / 128;
    const int E = in_sizes[1] / 2;
    const int M = in_sizes[2] / 128;

    char* p = (char*)d_ws;
    auto alloc = [&](size_t bytes) -> void* {
        void* r = (void*)p;
        p += (bytes + 255) & ~(size_t)255;
        return r;
    };
    int*   row_cnt    = (int*)alloc((size_t)N * 4);
    int*   col_cnt    = (int*)alloc((size_t)N * 4);
    int*   row_fill   = (int*)alloc((size_t)N * 4);
    int*   bc_cnt     = (int*)alloc((size_t)M * 4);
    size_t zero_bytes = (size_t)(p - (char*)d_ws);   // everything above must start at 0
    int*   row_ptr    = (int*)alloc((size_t)(N + 1) * 4);
    int*   bsums      = (int*)alloc(1024 * 4);
    float* dvec       = (float*)alloc((size_t)N * 4);
    float* dcol       = (float*)alloc((size_t)M * 4);
    float* ZW         = (float*)alloc((size_t)M * 128 * 4);
    float* ZA         = (float*)alloc((size_t)M * 128 * 4);
    int*   col_sorted = (int*)alloc((size_t)E * 4);
    float* G          = (float*)alloc((size_t)N * 128 * 4);

    hipMemsetAsync(d_ws, 0, zero_bytes, stream);

    int nbE = (E + 255) / 256;
    int nbN = (N + 255) / 256;
    k_edge_hist<<<nbE, 256, 0, stream>>>(ei, E, row_cnt, col_cnt);
    k_bc_hist<<<nbN, 256, 0, stream>>>(assign, N, bc_cnt);
    k_deg<<<nbN, 256, 0, stream>>>(col_cnt, bc_cnt, N, M, dvec, dcol);
    k_bc_gemm<<<M, 128, 0, stream>>>(bcf, WZ, WA, ZW, ZA);

    int nscan = (N + 1023) / 1024;
    k_scanA<<<nscan, 1024, 0, stream>>>(row_cnt, N, row_ptr, bsums);
    k_scanB<<<1, 1, 0, stream>>>(bsums, nscan);
    k_scanC<<<(N + 1 + 255) / 256, 256, 0, stream>>>(row_ptr, bsums, N, E);
    k_bucket<<<nbE, 256, 0, stream>>>(ei, E, row_ptr, row_fill, col_sorted);

    k_G<<<(N + GB_ROWS - 1) / GB_ROWS, 256, 0, stream>>>(x, WX, ZA, assign, dcol, G, N, M);
    k_final<<<(N + 3) / 4, 256, 0, stream>>>(G, dvec, row_ptr, col_sorted, ZW, dcol, assign, out, N, M);
}

// Round 5
// 535.646 us; speedup vs baseline: 1.2040x; 1.2040x over previous
//
#include <hip/hip_runtime.h>

#define RSQRT2 0.70710678118654752f

typedef unsigned int uint;

// bf16x2 pack (RTNE) / unpack
__device__ __forceinline__ uint pack_bf16x2(float a, float b) {
    uint ua = __float_as_uint(a), ub = __float_as_uint(b);
    ua += 0x7FFFu + ((ua >> 16) & 1u);
    ub += 0x7FFFu + ((ub >> 16) & 1u);
    return (ua >> 16) | (ub & 0xFFFF0000u);
}
__device__ __forceinline__ float blo(uint g) { return __uint_as_float(g << 16); }
__device__ __forceinline__ float bhi(uint g) { return __uint_as_float(g & 0xFFFF0000u); }

// ---------------- fused histograms ----------------

__global__ void k_hist(const int* __restrict__ ei, int E,
                       const int* __restrict__ assign, int N,
                       int* __restrict__ row_cnt, int* __restrict__ col_cnt,
                       int* __restrict__ bc_cnt) {
    int t = blockIdx.x * 256 + threadIdx.x;
    if (t < E) {
        atomicAdd(&row_cnt[ei[t]], 1);        // edge_index[0] = row
        atomicAdd(&col_cnt[ei[E + t]], 1);    // edge_index[1] = col
    }
    if (t < N) atomicAdd(&bc_cnt[assign[t]], 1);
}

// ---------------- exclusive scan over row_cnt -> row_ptr ----------------

__global__ void k_scanA(const int* __restrict__ cnt, int n,
                        int* __restrict__ out, int* __restrict__ bsums) {
    __shared__ int sm[1024];
    int t = threadIdx.x;
    int gid = blockIdx.x * 1024 + t;
    int v = (gid < n) ? cnt[gid] : 0;
    sm[t] = v;
    __syncthreads();
    for (int off = 1; off < 1024; off <<= 1) {
        int u = (t >= off) ? sm[t - off] : 0;
        __syncthreads();
        sm[t] += u;
        __syncthreads();
    }
    if (gid < n) out[gid] = sm[t] - v;           // exclusive
    if (t == 1023) bsums[blockIdx.x] = sm[1023]; // block total
}

__global__ void k_scanB(int* __restrict__ bsums, int nb) {
    if (threadIdx.x == 0 && blockIdx.x == 0) {
        int run = 0;
        for (int i = 0; i < nb; ++i) { int v = bsums[i]; bsums[i] = run; run += v; }
    }
}

// scanC + degree vectors fused (both only need completed histograms / bsums)
__global__ void k_scanC_deg(int* __restrict__ row_ptr, const int* __restrict__ bsums,
                            const int* __restrict__ col_cnt, const int* __restrict__ bc_cnt,
                            int n, int M, int E,
                            float* __restrict__ d, float* __restrict__ dcol) {
    int gid = blockIdx.x * 256 + threadIdx.x;
    if (gid < n) {
        row_ptr[gid] += bsums[gid >> 10];
        d[gid] = rsqrtf(1.0f + (float)col_cnt[gid]);
    } else if (gid == n) {
        row_ptr[n] = E;
    }
    if (gid < M) dcol[gid] = rsqrtf(1.0f + (float)bc_cnt[gid]);
}

// ---------------- bucket edges by row (CSR) ----------------

__global__ void k_bucket(const int* __restrict__ ei, int E,
                         const int* __restrict__ row_ptr, int* __restrict__ row_fill,
                         int* __restrict__ col_sorted) {
    int e = blockIdx.x * 256 + threadIdx.x;
    if (e < E) {
        int r = ei[e];
        int pos = atomicAdd(&row_fill[r], 1);
        col_sorted[row_ptr[r] + pos] = ei[E + e];
    }
}

// ---------------- small GEMMs: ZW = bcf@WZ, ZA = bcf@Walpha ----------------
// 16 bcf rows per block: weights read ceil(M/16)x(2x64KB) = 8 MB (was 131 MB).

__global__ __launch_bounds__(128) void k_bc_gemm(
    const float* __restrict__ bcf, const float* __restrict__ WZ,
    const float* __restrict__ WA, float* __restrict__ ZW, float* __restrict__ ZA, int M) {
    __shared__ float rows[16][128];
    int c = threadIdx.x;
    int r0 = blockIdx.x * 16;
    int nr = M - r0; if (nr > 16) nr = 16;
    for (int idx = c; idx < nr * 128; idx += 128)
        rows[idx >> 7][idx & 127] = bcf[r0 * 128 + idx];
    __syncthreads();
    float aW[16], aA[16];
#pragma unroll
    for (int r = 0; r < 16; ++r) { aW[r] = 0.f; aA[r] = 0.f; }
#pragma unroll 4
    for (int k = 0; k < 128; ++k) {
        float wz = WZ[k * 128 + c];
        float wa = WA[k * 128 + c];
#pragma unroll
        for (int r = 0; r < 16; ++r) {
            float xv = rows[r][k];          // same addr for all lanes -> broadcast
            aW[r] = fmaf(xv, wz, aW[r]);
            aA[r] = fmaf(xv, wa, aA[r]);
        }
    }
    for (int r = 0; r < nr; ++r) {
        ZW[(r0 + r) * 128 + c] = aW[r];
        ZA[(r0 + r) * 128 + c] = aA[r];
    }
}

// ---------------- G = x@WX + bhat(ZA), stored packed bf16x2 ----------------
// block: 256 threads -> 64 rows x 128 cols tile; thread: 4 rows x 8 cols micro-tile.

#define GB_ROWS 64
#define GB_KC 64

__global__ __launch_bounds__(256) void k_G(
    const float* __restrict__ x, const float* __restrict__ WX,
    const float* __restrict__ ZA, const int* __restrict__ assign,
    const float* __restrict__ dcol, uint* __restrict__ Gp, int N, int M) {
    __shared__ float xs[GB_ROWS][GB_KC + 1];   // same-addr broadcast per 16-lane group
    __shared__ float ws[GB_KC][128];

    int tid = threadIdx.x;
    int tc = tid & 15;    // col group: c0 = tc*8
    int tr = tid >> 4;    // row group: rows tr*4 .. tr*4+3
    int row0 = blockIdx.x * GB_ROWS;
    int c0 = tc * 8;

    float acc[4][8];
#pragma unroll
    for (int r = 0; r < 4; ++r)
#pragma unroll
        for (int j = 0; j < 8; ++j) acc[r][j] = 0.f;

    bool full = (row0 + GB_ROWS <= N);

    for (int kc = 0; kc < 128; kc += GB_KC) {
        // x tile: float4 global loads (16 lanes x 16B = 256B per row)
        if (full) {
#pragma unroll
            for (int it = 0; it < 4; ++it) {
                int idx = tid + 256 * it;           // 1024 float4s
                int r = idx >> 4, k4 = (idx & 15) * 4;
                float4 v = *(const float4*)&x[(size_t)(row0 + r) * 128 + kc + k4];
                xs[r][k4] = v.x; xs[r][k4 + 1] = v.y; xs[r][k4 + 2] = v.z; xs[r][k4 + 3] = v.w;
            }
        } else {
            for (int idx = tid; idx < GB_ROWS * GB_KC; idx += 256) {
                int r = idx >> 6, k = idx & 63;
                int gr = row0 + r;
                xs[r][k] = (gr < N) ? x[(size_t)gr * 128 + kc + k] : 0.f;
            }
        }
        // WX tile: float4
#pragma unroll
        for (int it = 0; it < 8; ++it) {
            int idx = tid + 256 * it;               // 2048 float4s
            int k = idx >> 5, c4 = (idx & 31) * 4;
            float4 v = *(const float4*)&WX[(size_t)(kc + k) * 128 + c4];
            ws[k][c4] = v.x; ws[k][c4 + 1] = v.y; ws[k][c4 + 2] = v.z; ws[k][c4 + 3] = v.w;
        }
        __syncthreads();
#pragma unroll 4
        for (int k = 0; k < GB_KC; ++k) {
            float a0 = xs[tr * 4 + 0][k];
            float a1 = xs[tr * 4 + 1][k];
            float a2 = xs[tr * 4 + 2][k];
            float a3 = xs[tr * 4 + 3][k];
            float4 b0 = *(const float4*)&ws[k][c0];
            float4 b1 = *(const float4*)&ws[k][c0 + 4];
            float bv[8] = {b0.x, b0.y, b0.z, b0.w, b1.x, b1.y, b1.z, b1.w};
#pragma unroll
            for (int j = 0; j < 8; ++j) {
                float b = bv[j];
                acc[0][j] = fmaf(a0, b, acc[0][j]);
                acc[1][j] = fmaf(a1, b, acc[1][j]);
                acc[2][j] = fmaf(a2, b, acc[2][j]);
                acc[3][j] = fmaf(a3, b, acc[3][j]);
            }
        }
        __syncthreads();
    }

    // epilogue: v = xWX + drow*(dcol[a]*ZA[a][c] + (gr<M ? dcol[gr]*ZA[gr][c] : 0)); pack bf16
#pragma unroll
    for (int rr = 0; rr < 4; ++rr) {
        int gr = row0 + tr * 4 + rr;
        if (gr >= N) continue;
        int ai = assign[gr];
        float dca = dcol[ai];
        float dr = (gr < M) ? RSQRT2 : 1.0f;
        float dci = (gr < M) ? dcol[gr] : 0.0f;
        float v[8];
#pragma unroll
        for (int j = 0; j < 8; ++j) {
            float bh = dca * ZA[ai * 128 + c0 + j];
            if (gr < M) bh = fmaf(dci, ZA[gr * 128 + c0 + j], bh);
            v[j] = acc[rr][j] + bh * dr;
        }
        uint4 w;
        w.x = pack_bf16x2(v[0], v[1]);
        w.y = pack_bf16x2(v[2], v[3]);
        w.z = pack_bf16x2(v[4], v[5]);
        w.w = pack_bf16x2(v[6], v[7]);
        *(uint4*)&Gp[(size_t)gr * 64 + (c0 >> 1)] = w;   // 16B aligned: c0/2 = tc*4
    }
}

// ---------------- final: out = (d*(gather + d*G) + Zprime)/3 ----------------
// one wave per node; lane handles dims (2l, 2l+1) via one packed uint (4B/lane).

__global__ __launch_bounds__(256) void k_final(
    const uint* __restrict__ Gp, const float* __restrict__ d,
    const int* __restrict__ row_ptr, const int* __restrict__ col_sorted,
    const float* __restrict__ ZW, const float* __restrict__ dcol,
    const int* __restrict__ assign, float* __restrict__ out, int N, int M) {
    int wid = threadIdx.x >> 6;
    int lane = threadIdx.x & 63;
    int i = blockIdx.x * 4 + wid;
    if (i >= N) return;

    int s = row_ptr[i];
    int e = row_ptr[i + 1];
    float ax = 0.f, ay = 0.f;
    int j = s;
    for (; j + 4 <= e; j += 4) {                 // 4 independent col->G load chains
        int c0 = col_sorted[j];
        int c1 = col_sorted[j + 1];
        int c2 = col_sorted[j + 2];
        int c3 = col_sorted[j + 3];
        uint g0 = Gp[(size_t)c0 * 64 + lane];
        uint g1 = Gp[(size_t)c1 * 64 + lane];
        uint g2 = Gp[(size_t)c2 * 64 + lane];
        uint g3 = Gp[(size_t)c3 * 64 + lane];
        float d0 = d[c0], d1 = d[c1], d2 = d[c2], d3 = d[c3];
        ax = fmaf(d0, blo(g0), ax); ay = fmaf(d0, bhi(g0), ay);
        ax = fmaf(d1, blo(g1), ax); ay = fmaf(d1, bhi(g1), ay);
        ax = fmaf(d2, blo(g2), ax); ay = fmaf(d2, bhi(g2), ay);
        ax = fmaf(d3, blo(g3), ax); ay = fmaf(d3, bhi(g3), ay);
    }
    for (; j < e; ++j) {
        int c = col_sorted[j];
        uint g = Gp[(size_t)c * 64 + lane];
        float dc = d[c];
        ax = fmaf(dc, blo(g), ax);
        ay = fmaf(dc, bhi(g), ay);
    }
    float di = d[i];
    uint gi = Gp[(size_t)i * 64 + lane];
    float ox = di * fmaf(di, blo(gi), ax);
    float oy = di * fmaf(di, bhi(gi), ay);

    int ai = assign[i];
    float dca = dcol[ai];
    const float2* ZW2 = (const float2*)ZW;
    float2 zw = ZW2[ai * 64 + lane];
    float zx = dca * zw.x, zy = dca * zw.y;
    if (i < M) {
        float dci = dcol[i];
        float2 zwi = ZW2[i * 64 + lane];
        zx = fmaf(dci, zwi.x, zx);
        zy = fmaf(dci, zwi.y, zy);
    }
    float dr = (i < M) ? RSQRT2 : 1.0f;

    float2 o;
    o.x = (ox + zx * dr) * (1.0f / 3.0f);
    o.y = (oy + zy * dr) * (1.0f / 3.0f);
    ((float2*)out)[(size_t)i * 64 + lane] = o;
}

// ---------------- launch ----------------

extern "C" void kernel_launch(void* const* d_in, const int* in_sizes, int n_in,
                              void* d_out, int out_size, void* d_ws, size_t ws_size,
                              hipStream_t stream) {
    const float* x      = (const float*)d_in[0];
    const int*   ei     = (const int*)d_in[1];
    const float* bcf    = (const float*)d_in[2];
    const int*   assign = (const int*)d_in[3];
    const float* WX     = (const float*)d_in[4];
    const float* WZ     = (const float*)d_in[5];
    const float* WA     = (const float*)d_in[6];
    float* out = (float*)d_out;

    const int N = in_sizes[0] / 128;
    const int E = in_sizes[1] / 2;
    const int M = in_sizes[2] / 128;

    char* p = (char*)d_ws;
    auto alloc = [&](size_t bytes) -> void* {
        void* r = (void*)p;
        p += (bytes + 255) & ~(size_t)255;
        return r;
    };
    int*   row_cnt    = (int*)alloc((size_t)N * 4);
    int*   col_cnt    = (int*)alloc((size_t)N * 4);
    int*   row_fill   = (int*)alloc((size_t)N * 4);
    int*   bc_cnt     = (int*)alloc((size_t)M * 4);
    size_t zero_bytes = (size_t)(p - (char*)d_ws);   // atomic counters must start at 0
    int*   row_ptr    = (int*)alloc((size_t)(N + 1) * 4);
    int*   bsums      = (int*)alloc(1024 * 4);
    float* dvec       = (float*)alloc((size_t)N * 4);
    float* dcol       = (float*)alloc((size_t)M * 4);
    float* ZW         = (float*)alloc((size_t)M * 128 * 4);
    float* ZA         = (float*)alloc((size_t)M * 128 * 4);
    int*   col_sorted = (int*)alloc((size_t)E * 4);
    uint*  Gp         = (uint*)alloc((size_t)N * 64 * 4);   // packed bf16x2

    hipMemsetAsync(d_ws, 0, zero_bytes, stream);

    int nbE = (E + 255) / 256;
    k_hist<<<nbE, 256, 0, stream>>>(ei, E, assign, N, row_cnt, col_cnt, bc_cnt);
    k_bc_gemm<<<(M + 15) / 16, 128, 0, stream>>>(bcf, WZ, WA, ZW, ZA, M);

    int nscan = (N + 1023) / 1024;
    k_scanA<<<nscan, 1024, 0, stream>>>(row_cnt, N, row_ptr, bsums);
    k_scanB<<<1, 1, 0, stream>>>(bsums, nscan);
    k_scanC_deg<<<(N + 1 + 255) / 256, 256, 0, stream>>>(row_ptr, bsums, col_cnt, bc_cnt,
                                                         N, M, E, dvec, dcol);
    k_bucket<<<nbE, 256, 0, stream>>>(ei, E, row_ptr, row_fill, col_sorted);

    k_G<<<(N + GB_ROWS - 1) / GB_ROWS, 256, 0, stream>>>(x, WX, ZA, assign, dcol, Gp, N, M);
    k_final<<<(N + 3) / 4, 256, 0, stream>>>(Gp, dvec, row_ptr, col_sorted, ZW, dcol, assign, out, N, M);
}

// Round 6
// 356.276 us; speedup vs baseline: 1.8102x; 1.5035x over previous
//
#include <hip/hip_runtime.h>

#define RSQRT2 0.70710678118654752f

typedef unsigned int uint;
typedef unsigned char uchar;

#define MAXNB 512          // max coarse buckets (supports N <= 131072)
#define EPB   4096         // edges per block in coarse/scatter kernels

// bf16x2 pack (RTNE) / unpack
__device__ __forceinline__ uint pack_bf16x2(float a, float b) {
    uint ua = __float_as_uint(a), ub = __float_as_uint(b);
    ua += 0x7FFFu + ((ua >> 16) & 1u);
    ub += 0x7FFFu + ((ub >> 16) & 1u);
    return (ua >> 16) | (ub & 0xFFFF0000u);
}
__device__ __forceinline__ float blo(uint g) { return __uint_as_float(g << 16); }
__device__ __forceinline__ float bhi(uint g) { return __uint_as_float(g & 0xFFFF0000u); }

// ---- K1: coarse histograms (row>>8, col>>8) LDS-privatized + bc_cnt ----

__global__ __launch_bounds__(256) void k_coarse(
    const int* __restrict__ ei, int E,
    const int* __restrict__ assign, int N, int NB,
    int* __restrict__ coarse_row, int* __restrict__ coarse_col,
    int* __restrict__ bc_cnt) {
    __shared__ int lr[MAXNB], lc[MAXNB];
    int t = threadIdx.x;
    for (int i = t; i < NB; i += 256) { lr[i] = 0; lc[i] = 0; }
    __syncthreads();
    int base = blockIdx.x * EPB;
#pragma unroll
    for (int k = 0; k < 16; ++k) {
        int e = base + t + k * 256;
        if (e < E) {
            atomicAdd(&lr[ei[e] >> 8], 1);
            atomicAdd(&lc[ei[E + e] >> 8], 1);
        }
    }
    int i = blockIdx.x * 256 + t;
    if (i < N) atomicAdd(&bc_cnt[assign[i]], 1);
    __syncthreads();
    for (int b = t; b < NB; b += 256) {
        if (lr[b]) atomicAdd(&coarse_row[b], lr[b]);
        if (lc[b]) atomicAdd(&coarse_col[b], lc[b]);
    }
}

// ---- K2: one-block scan of both coarse arrays + dcol + row_ptr[N] ----

__global__ __launch_bounds__(1024) void k_scan_small(
    const int* __restrict__ coarse_row, const int* __restrict__ coarse_col,
    const int* __restrict__ bc_cnt, int NB, int M, int E, int N,
    int* __restrict__ row_off, int* __restrict__ col_off,
    float* __restrict__ dcol, int* __restrict__ row_ptr) {
    __shared__ int sm[1024];
    int t = threadIdx.x;
    int half = t >> 9;          // 0: row, 1: col
    int lt = t & 511;
    int v = (lt < NB) ? (half ? coarse_col[lt] : coarse_row[lt]) : 0;
    sm[t] = v;
    __syncthreads();
    for (int off = 1; off < 512; off <<= 1) {
        int u = (lt >= off) ? sm[t - off] : 0;
        __syncthreads();
        sm[t] += u;
        __syncthreads();
    }
    // exclusive prefix; for lt in [NB,511] inclusive==total so off[NB]=E lands too
    if (lt <= NB) (half ? col_off : row_off)[lt] = sm[t] - v;
    for (int i = t; i < M; i += 1024) dcol[i] = rsqrtf(1.0f + (float)bc_cnt[i]);
    if (t == 0) row_ptr[N] = E;
}

// ---- K3: scatter edges into coarse buckets (one pass, privatized reservation) ----

__global__ __launch_bounds__(256) void k_scatter(
    const int* __restrict__ ei, int E, int NB,
    const int* __restrict__ row_off, const int* __restrict__ col_off,
    int* __restrict__ fill_row, int* __restrict__ fill_col,
    uint* __restrict__ packed, uchar* __restrict__ colb) {
    __shared__ int lr[MAXNB], lc[MAXNB], rbase[MAXNB], cbase[MAXNB];
    int t = threadIdx.x;
    for (int i = t; i < NB; i += 256) { lr[i] = 0; lc[i] = 0; }
    __syncthreads();
    int base = blockIdx.x * EPB;
#pragma unroll
    for (int k = 0; k < 16; ++k) {
        int e = base + t + k * 256;
        if (e < E) {
            atomicAdd(&lr[ei[e] >> 8], 1);
            atomicAdd(&lc[ei[E + e] >> 8], 1);
        }
    }
    __syncthreads();
    for (int b = t; b < NB; b += 256) {
        int cr = lr[b];
        if (cr) rbase[b] = row_off[b] + atomicAdd(&fill_row[b], cr);
        lr[b] = 0;
        int cc = lc[b];
        if (cc) cbase[b] = col_off[b] + atomicAdd(&fill_col[b], cc);
        lc[b] = 0;
    }
    __syncthreads();
#pragma unroll
    for (int k = 0; k < 16; ++k) {
        int e = base + t + k * 256;
        if (e < E) {
            int r = ei[e], c = ei[E + e];
            int rb = r >> 8, cb = c >> 8;
            int pr = atomicAdd(&lr[rb], 1);
            packed[rbase[rb] + pr] = ((uint)(r & 255) << 24) | (uint)c;
            int pc = atomicAdd(&lc[cb], 1);
            colb[cbase[cb] + pc] = (uchar)(c & 255);
        }
    }
}

// ---- K4r: per-bucket fine histogram + scan -> row_ptr; place col_sorted ----

__global__ __launch_bounds__(256) void k_fine_row(
    const uint* __restrict__ packed, const int* __restrict__ row_off,
    int N, int* __restrict__ row_ptr, int* __restrict__ col_sorted) {
    __shared__ int h[256], cur[256];
    int t = threadIdx.x, b = blockIdx.x;
    int s = row_off[b], e = row_off[b + 1];
    h[t] = 0;
    __syncthreads();
    for (int j = s + t; j < e; j += 256) atomicAdd(&h[packed[j] >> 24], 1);
    __syncthreads();
    int v = h[t];
    for (int off = 1; off < 256; off <<= 1) {
        int u = (t >= off) ? h[t - off] : 0;
        __syncthreads();
        h[t] += u;
        __syncthreads();
    }
    int excl = h[t] - v;
    cur[t] = excl;
    int gr = b * 256 + t;
    if (gr < N) row_ptr[gr] = s + excl;
    __syncthreads();
    for (int j = s + t; j < e; j += 256) {
        uint p = packed[j];
        int pos = atomicAdd(&cur[p >> 24], 1);
        col_sorted[s + pos] = (int)(p & 0xFFFFFFu);
    }
}

// ---- K4c: per-bucket fine col histogram -> d = rsqrt(1+cnt) ----

__global__ __launch_bounds__(256) void k_fine_col(
    const uchar* __restrict__ colb, const int* __restrict__ col_off,
    int N, float* __restrict__ d) {
    __shared__ int h[256];
    int t = threadIdx.x, b = blockIdx.x;
    int s = col_off[b], e = col_off[b + 1];
    h[t] = 0;
    __syncthreads();
    for (int j = s + t; j < e; j += 256) atomicAdd(&h[colb[j]], 1);
    __syncthreads();
    int gc = b * 256 + t;
    if (gc < N) d[gc] = rsqrtf(1.0f + (float)h[t]);
}

// ---------------- small GEMMs: ZW = bcf@WZ, ZA = bcf@Walpha ----------------

__global__ __launch_bounds__(128) void k_bc_gemm(
    const float* __restrict__ bcf, const float* __restrict__ WZ,
    const float* __restrict__ WA, float* __restrict__ ZW, float* __restrict__ ZA, int M) {
    __shared__ float rows[16][128];
    int c = threadIdx.x;
    int r0 = blockIdx.x * 16;
    int nr = M - r0; if (nr > 16) nr = 16;
    for (int idx = c; idx < nr * 128; idx += 128)
        rows[idx >> 7][idx & 127] = bcf[r0 * 128 + idx];
    __syncthreads();
    float aW[16], aA[16];
#pragma unroll
    for (int r = 0; r < 16; ++r) { aW[r] = 0.f; aA[r] = 0.f; }
#pragma unroll 4
    for (int k = 0; k < 128; ++k) {
        float wz = WZ[k * 128 + c];
        float wa = WA[k * 128 + c];
#pragma unroll
        for (int r = 0; r < 16; ++r) {
            float xv = rows[r][k];
            aW[r] = fmaf(xv, wz, aW[r]);
            aA[r] = fmaf(xv, wa, aA[r]);
        }
    }
    for (int r = 0; r < nr; ++r) {
        ZW[(r0 + r) * 128 + c] = aW[r];
        ZA[(r0 + r) * 128 + c] = aA[r];
    }
}

// ---------------- G = x@WX + bhat(ZA), stored packed bf16x2 ----------------

#define GB_ROWS 64
#define GB_KC 64

__global__ __launch_bounds__(256) void k_G(
    const float* __restrict__ x, const float* __restrict__ WX,
    const float* __restrict__ ZA, const int* __restrict__ assign,
    const float* __restrict__ dcol, uint* __restrict__ Gp, int N, int M) {
    __shared__ float xs[GB_ROWS][GB_KC + 1];
    __shared__ float ws[GB_KC][128];

    int tid = threadIdx.x;
    int tc = tid & 15;
    int tr = tid >> 4;
    int row0 = blockIdx.x * GB_ROWS;
    int c0 = tc * 8;

    float acc[4][8];
#pragma unroll
    for (int r = 0; r < 4; ++r)
#pragma unroll
        for (int j = 0; j < 8; ++j) acc[r][j] = 0.f;

    bool full = (row0 + GB_ROWS <= N);

    for (int kc = 0; kc < 128; kc += GB_KC) {
        if (full) {
#pragma unroll
            for (int it = 0; it < 4; ++it) {
                int idx = tid + 256 * it;
                int r = idx >> 4, k4 = (idx & 15) * 4;
                float4 v = *(const float4*)&x[(size_t)(row0 + r) * 128 + kc + k4];
                xs[r][k4] = v.x; xs[r][k4 + 1] = v.y; xs[r][k4 + 2] = v.z; xs[r][k4 + 3] = v.w;
            }
        } else {
            for (int idx = tid; idx < GB_ROWS * GB_KC; idx += 256) {
                int r = idx >> 6, k = idx & 63;
                int gr = row0 + r;
                xs[r][k] = (gr < N) ? x[(size_t)gr * 128 + kc + k] : 0.f;
            }
        }
#pragma unroll
        for (int it = 0; it < 8; ++it) {
            int idx = tid + 256 * it;
            int k = idx >> 5, c4 = (idx & 31) * 4;
            float4 v = *(const float4*)&WX[(size_t)(kc + k) * 128 + c4];
            ws[k][c4] = v.x; ws[k][c4 + 1] = v.y; ws[k][c4 + 2] = v.z; ws[k][c4 + 3] = v.w;
        }
        __syncthreads();
#pragma unroll 4
        for (int k = 0; k < GB_KC; ++k) {
            float a0 = xs[tr * 4 + 0][k];
            float a1 = xs[tr * 4 + 1][k];
            float a2 = xs[tr * 4 + 2][k];
            float a3 = xs[tr * 4 + 3][k];
            float4 b0 = *(const float4*)&ws[k][c0];
            float4 b1 = *(const float4*)&ws[k][c0 + 4];
            float bv[8] = {b0.x, b0.y, b0.z, b0.w, b1.x, b1.y, b1.z, b1.w};
#pragma unroll
            for (int j = 0; j < 8; ++j) {
                float b = bv[j];
                acc[0][j] = fmaf(a0, b, acc[0][j]);
                acc[1][j] = fmaf(a1, b, acc[1][j]);
                acc[2][j] = fmaf(a2, b, acc[2][j]);
                acc[3][j] = fmaf(a3, b, acc[3][j]);
            }
        }
        __syncthreads();
    }

#pragma unroll
    for (int rr = 0; rr < 4; ++rr) {
        int gr = row0 + tr * 4 + rr;
        if (gr >= N) continue;
        int ai = assign[gr];
        float dca = dcol[ai];
        float dr = (gr < M) ? RSQRT2 : 1.0f;
        float dci = (gr < M) ? dcol[gr] : 0.0f;
        float v[8];
#pragma unroll
        for (int j = 0; j < 8; ++j) {
            float bh = dca * ZA[ai * 128 + c0 + j];
            if (gr < M) bh = fmaf(dci, ZA[gr * 128 + c0 + j], bh);
            v[j] = acc[rr][j] + bh * dr;
        }
        uint4 w;
        w.x = pack_bf16x2(v[0], v[1]);
        w.y = pack_bf16x2(v[2], v[3]);
        w.z = pack_bf16x2(v[4], v[5]);
        w.w = pack_bf16x2(v[6], v[7]);
        *(uint4*)&Gp[(size_t)gr * 64 + (c0 >> 1)] = w;
    }
}

// ---------------- final: out = (d*(gather + d*G) + Zprime)/3 ----------------

__global__ __launch_bounds__(256) void k_final(
    const uint* __restrict__ Gp, const float* __restrict__ d,
    const int* __restrict__ row_ptr, const int* __restrict__ col_sorted,
    const float* __restrict__ ZW, const float* __restrict__ dcol,
    const int* __restrict__ assign, float* __restrict__ out, int N, int M) {
    int wid = threadIdx.x >> 6;
    int lane = threadIdx.x & 63;
    int i = blockIdx.x * 4 + wid;
    if (i >= N) return;

    int s = row_ptr[i];
    int e = row_ptr[i + 1];
    float ax = 0.f, ay = 0.f;
    int j = s;
    for (; j + 4 <= e; j += 4) {
        int c0 = col_sorted[j];
        int c1 = col_sorted[j + 1];
        int c2 = col_sorted[j + 2];
        int c3 = col_sorted[j + 3];
        uint g0 = Gp[(size_t)c0 * 64 + lane];
        uint g1 = Gp[(size_t)c1 * 64 + lane];
        uint g2 = Gp[(size_t)c2 * 64 + lane];
        uint g3 = Gp[(size_t)c3 * 64 + lane];
        float d0 = d[c0], d1 = d[c1], d2 = d[c2], d3 = d[c3];
        ax = fmaf(d0, blo(g0), ax); ay = fmaf(d0, bhi(g0), ay);
        ax = fmaf(d1, blo(g1), ax); ay = fmaf(d1, bhi(g1), ay);
        ax = fmaf(d2, blo(g2), ax); ay = fmaf(d2, bhi(g2), ay);
        ax = fmaf(d3, blo(g3), ax); ay = fmaf(d3, bhi(g3), ay);
    }
    for (; j < e; ++j) {
        int c = col_sorted[j];
        uint g = Gp[(size_t)c * 64 + lane];
        float dc = d[c];
        ax = fmaf(dc, blo(g), ax);
        ay = fmaf(dc, bhi(g), ay);
    }
    float di = d[i];
    uint gi = Gp[(size_t)i * 64 + lane];
    float ox = di * fmaf(di, blo(gi), ax);
    float oy = di * fmaf(di, bhi(gi), ay);

    int ai = assign[i];
    float dca = dcol[ai];
    const float2* ZW2 = (const float2*)ZW;
    float2 zw = ZW2[ai * 64 + lane];
    float zx = dca * zw.x, zy = dca * zw.y;
    if (i < M) {
        float dci = dcol[i];
        float2 zwi = ZW2[i * 64 + lane];
        zx = fmaf(dci, zwi.x, zx);
        zy = fmaf(dci, zwi.y, zy);
    }
    float dr = (i < M) ? RSQRT2 : 1.0f;

    float2 o;
    o.x = (ox + zx * dr) * (1.0f / 3.0f);
    o.y = (oy + zy * dr) * (1.0f / 3.0f);
    ((float2*)out)[(size_t)i * 64 + lane] = o;
}

// ---------------- launch ----------------

extern "C" void kernel_launch(void* const* d_in, const int* in_sizes, int n_in,
                              void* d_out, int out_size, void* d_ws, size_t ws_size,
                              hipStream_t stream) {
    const float* x      = (const float*)d_in[0];
    const int*   ei     = (const int*)d_in[1];
    const float* bcf    = (const float*)d_in[2];
    const int*   assign = (const int*)d_in[3];
    const float* WX     = (const float*)d_in[4];
    const float* WZ     = (const float*)d_in[5];
    const float* WA     = (const float*)d_in[6];
    float* out = (float*)d_out;

    const int N = in_sizes[0] / 128;
    const int E = in_sizes[1] / 2;
    const int M = in_sizes[2] / 128;
    const int NB = (N + 255) >> 8;      // coarse buckets of 256 rows (<= MAXNB)

    char* p = (char*)d_ws;
    auto alloc = [&](size_t bytes) -> void* {
        void* r = (void*)p;
        p += (bytes + 255) & ~(size_t)255;
        return r;
    };
    int*   coarse_row = (int*)alloc(MAXNB * 4);
    int*   coarse_col = (int*)alloc(MAXNB * 4);
    int*   fill_row   = (int*)alloc(MAXNB * 4);
    int*   fill_col   = (int*)alloc(MAXNB * 4);
    int*   bc_cnt     = (int*)alloc((size_t)M * 4);
    size_t zero_bytes = (size_t)(p - (char*)d_ws);   // atomic counters must start at 0
    int*   row_off    = (int*)alloc((MAXNB + 1) * 4);
    int*   col_off    = (int*)alloc((MAXNB + 1) * 4);
    int*   row_ptr    = (int*)alloc((size_t)(N + 1) * 4);
    float* dvec       = (float*)alloc((size_t)N * 4);
    float* dcol       = (float*)alloc((size_t)M * 4);
    float* ZW         = (float*)alloc((size_t)M * 128 * 4);
    float* ZA         = (float*)alloc((size_t)M * 128 * 4);
    uint*  packed     = (uint*)alloc((size_t)E * 4);
    uchar* colb       = (uchar*)alloc((size_t)E);
    int*   col_sorted = (int*)alloc((size_t)E * 4);
    uint*  Gp         = (uint*)alloc((size_t)N * 64 * 4);   // packed bf16x2

    hipMemsetAsync(d_ws, 0, zero_bytes, stream);

    int nbE = (E + EPB - 1) / EPB;
    int nbN = (N + 255) / 256;
    int nbK1 = nbE > nbN ? nbE : nbN;

    k_coarse<<<nbK1, 256, 0, stream>>>(ei, E, assign, N, NB, coarse_row, coarse_col, bc_cnt);
    k_bc_gemm<<<(M + 15) / 16, 128, 0, stream>>>(bcf, WZ, WA, ZW, ZA, M);
    k_scan_small<<<1, 1024, 0, stream>>>(coarse_row, coarse_col, bc_cnt, NB, M, E, N,
                                         row_off, col_off, dcol, row_ptr);
    k_scatter<<<nbE, 256, 0, stream>>>(ei, E, NB, row_off, col_off,
                                       fill_row, fill_col, packed, colb);
    k_fine_row<<<NB, 256, 0, stream>>>(packed, row_off, N, row_ptr, col_sorted);
    k_fine_col<<<NB, 256, 0, stream>>>(colb, col_off, N, dvec);

    k_G<<<(N + GB_ROWS - 1) / GB_ROWS, 256, 0, stream>>>(x, WX, ZA, assign, dcol, Gp, N, M);
    k_final<<<(N + 3) / 4, 256, 0, stream>>>(Gp, dvec, row_ptr, col_sorted, ZW, dcol, assign, out, N, M);
}

// Round 9
// 348.879 us; speedup vs baseline: 1.8486x; 1.0212x over previous
//
#include <hip/hip_runtime.h>

#define RSQRT2 0.70710678118654752f

typedef unsigned int uint;
typedef unsigned char uchar;
typedef __attribute__((ext_vector_type(8))) short bf16x8;
typedef __attribute__((ext_vector_type(4))) float f32x4;

#define MAXNB 512          // max coarse buckets (supports N <= 131072)
#define EPB   4096         // edges per block in coarse/scatter kernels

// bf16x2 pack (RTNE) / unpack
__device__ __forceinline__ uint pack_bf16x2(float a, float b) {
    uint ua = __float_as_uint(a), ub = __float_as_uint(b);
    ua += 0x7FFFu + ((ua >> 16) & 1u);
    ub += 0x7FFFu + ((ub >> 16) & 1u);
    return (ua >> 16) | (ub & 0xFFFF0000u);
}
__device__ __forceinline__ float blo(uint g) { return __uint_as_float(g << 16); }
__device__ __forceinline__ float bhi(uint g) { return __uint_as_float(g & 0xFFFF0000u); }

// ---- K1: coarse histograms (row>>8, col>>8) LDS-privatized + bc_cnt ----

__global__ __launch_bounds__(256) void k_coarse(
    const int* __restrict__ ei, int E,
    const int* __restrict__ assign, int N, int NB,
    int* __restrict__ coarse_row, int* __restrict__ coarse_col,
    int* __restrict__ bc_cnt) {
    __shared__ int lr[MAXNB], lc[MAXNB];
    int t = threadIdx.x;
    for (int i = t; i < NB; i += 256) { lr[i] = 0; lc[i] = 0; }
    __syncthreads();
    int base = blockIdx.x * EPB;
#pragma unroll
    for (int k = 0; k < 16; ++k) {
        int e = base + t + k * 256;
        if (e < E) {
            atomicAdd(&lr[ei[e] >> 8], 1);
            atomicAdd(&lc[ei[E + e] >> 8], 1);
        }
    }
    int i = blockIdx.x * 256 + t;
    if (i < N) atomicAdd(&bc_cnt[assign[i]], 1);
    __syncthreads();
    for (int b = t; b < NB; b += 256) {
        if (lr[b]) atomicAdd(&coarse_row[b], lr[b]);
        if (lc[b]) atomicAdd(&coarse_col[b], lc[b]);
    }
}

// ---- K2: one-block scan of both coarse arrays + dcol + row_ptr[N] ----

__global__ __launch_bounds__(1024) void k_scan_small(
    const int* __restrict__ coarse_row, const int* __restrict__ coarse_col,
    const int* __restrict__ bc_cnt, int NB, int M, int E, int N,
    int* __restrict__ row_off, int* __restrict__ col_off,
    float* __restrict__ dcol, int* __restrict__ row_ptr) {
    __shared__ int sm[1024];
    int t = threadIdx.x;
    int half = t >> 9;          // 0: row, 1: col
    int lt = t & 511;
    int v = (lt < NB) ? (half ? coarse_col[lt] : coarse_row[lt]) : 0;
    sm[t] = v;
    __syncthreads();
    for (int off = 1; off < 512; off <<= 1) {
        int u = (lt >= off) ? sm[t - off] : 0;
        __syncthreads();
        sm[t] += u;
        __syncthreads();
    }
    if (lt <= NB) (half ? col_off : row_off)[lt] = sm[t] - v;
    for (int i = t; i < M; i += 1024) dcol[i] = rsqrtf(1.0f + (float)bc_cnt[i]);
    if (t == 0) row_ptr[N] = E;
}

// ---- K3: scatter edges into coarse buckets ----

__global__ __launch_bounds__(256) void k_scatter(
    const int* __restrict__ ei, int E, int NB,
    const int* __restrict__ row_off, const int* __restrict__ col_off,
    int* __restrict__ fill_row, int* __restrict__ fill_col,
    uint* __restrict__ packed, uchar* __restrict__ colb) {
    __shared__ int lr[MAXNB], lc[MAXNB], rbase[MAXNB], cbase[MAXNB];
    int t = threadIdx.x;
    for (int i = t; i < NB; i += 256) { lr[i] = 0; lc[i] = 0; }
    __syncthreads();
    int base = blockIdx.x * EPB;
#pragma unroll
    for (int k = 0; k < 16; ++k) {
        int e = base + t + k * 256;
        if (e < E) {
            atomicAdd(&lr[ei[e] >> 8], 1);
            atomicAdd(&lc[ei[E + e] >> 8], 1);
        }
    }
    __syncthreads();
    for (int b = t; b < NB; b += 256) {
        int cr = lr[b];
        if (cr) rbase[b] = row_off[b] + atomicAdd(&fill_row[b], cr);
        lr[b] = 0;
        int cc = lc[b];
        if (cc) cbase[b] = col_off[b] + atomicAdd(&fill_col[b], cc);
        lc[b] = 0;
    }
    __syncthreads();
#pragma unroll
    for (int k = 0; k < 16; ++k) {
        int e = base + t + k * 256;
        if (e < E) {
            int r = ei[e], c = ei[E + e];
            int rb = r >> 8, cb = c >> 8;
            int pr = atomicAdd(&lr[rb], 1);
            packed[rbase[rb] + pr] = ((uint)(r & 255) << 24) | (uint)c;
            int pc = atomicAdd(&lc[cb], 1);
            colb[cbase[cb] + pc] = (uchar)(c & 255);
        }
    }
}

// ---- K4r: per-bucket fine histogram + scan -> row_ptr; place col_sorted ----

__global__ __launch_bounds__(256) void k_fine_row(
    const uint* __restrict__ packed, const int* __restrict__ row_off,
    int N, int* __restrict__ row_ptr, int* __restrict__ col_sorted) {
    __shared__ int h[256], cur[256];
    int t = threadIdx.x, b = blockIdx.x;
    int s = row_off[b], e = row_off[b + 1];
    h[t] = 0;
    __syncthreads();
    for (int j = s + t; j < e; j += 256) atomicAdd(&h[packed[j] >> 24], 1);
    __syncthreads();
    int v = h[t];
    for (int off = 1; off < 256; off <<= 1) {
        int u = (t >= off) ? h[t - off] : 0;
        __syncthreads();
        h[t] += u;
        __syncthreads();
    }
    int excl = h[t] - v;
    cur[t] = excl;
    int gr = b * 256 + t;
    if (gr < N) row_ptr[gr] = s + excl;
    __syncthreads();
    for (int j = s + t; j < e; j += 256) {
        uint p = packed[j];
        int pos = atomicAdd(&cur[p >> 24], 1);
        col_sorted[s + pos] = (int)(p & 0xFFFFFFu);
    }
}

// ---- K4c: per-bucket fine col histogram -> d = rsqrt(1+cnt) ----

__global__ __launch_bounds__(256) void k_fine_col(
    const uchar* __restrict__ colb, const int* __restrict__ col_off,
    int N, float* __restrict__ d) {
    __shared__ int h[256];
    int t = threadIdx.x, b = blockIdx.x;
    int s = col_off[b], e = col_off[b + 1];
    h[t] = 0;
    __syncthreads();
    for (int j = s + t; j < e; j += 256) atomicAdd(&h[colb[j]], 1);
    __syncthreads();
    int gc = b * 256 + t;
    if (gc < N) d[gc] = rsqrtf(1.0f + (float)h[t]);
}

// ---------------- small GEMMs: ZW = bcf@WZ, ZA = bcf@Walpha ----------------

__global__ __launch_bounds__(128) void k_bc_gemm(
    const float* __restrict__ bcf, const float* __restrict__ WZ,
    const float* __restrict__ WA, float* __restrict__ ZW, float* __restrict__ ZA, int M) {
    __shared__ float rows[16][128];
    int c = threadIdx.x;
    int r0 = blockIdx.x * 16;
    int nr = M - r0; if (nr > 16) nr = 16;
    for (int idx = c; idx < nr * 128; idx += 128)
        rows[idx >> 7][idx & 127] = bcf[r0 * 128 + idx];
    __syncthreads();
    float aW[16], aA[16];
#pragma unroll
    for (int r = 0; r < 16; ++r) { aW[r] = 0.f; aA[r] = 0.f; }
#pragma unroll 4
    for (int k = 0; k < 128; ++k) {
        float wz = WZ[k * 128 + c];
        float wa = WA[k * 128 + c];
#pragma unroll
        for (int r = 0; r < 16; ++r) {
            float xv = rows[r][k];
            aW[r] = fmaf(xv, wz, aW[r]);
            aA[r] = fmaf(xv, wa, aA[r]);
        }
    }
    for (int r = 0; r < nr; ++r) {
        ZW[(r0 + r) * 128 + c] = aW[r];
        ZA[(r0 + r) * 128 + c] = aA[r];
    }
}

// ---------------- k_G: G' = d * (x@WX + bhat(ZA)), MFMA bf16, no LDS ------
// wave = 32 rows x 128 cols (2 row-tiles of 16). A from x (global, cvt bf16),
// B from WX (global, L2-hot, cvt bf16). acc f32. Epilogue folds bhat + d,
// packs bf16x2 via shfl_xor lane pairing.

__global__ __launch_bounds__(256) void k_G(
    const float* __restrict__ x, const float* __restrict__ WX,
    const float* __restrict__ ZA, const int* __restrict__ assign,
    const float* __restrict__ dcol, const float* __restrict__ dvec,
    uint* __restrict__ Gp, int N, int M) {
    int lane = threadIdx.x & 63;
    int wid = threadIdx.x >> 6;
    int r0 = blockIdx.x * 128 + wid * 32;       // this wave: rows r0..r0+31
    int lrow = lane & 15;
    int lg = lane >> 4;                          // k-group 0..3

    f32x4 acc[2][8];
#pragma unroll
    for (int rt = 0; rt < 2; ++rt)
#pragma unroll
        for (int ct = 0; ct < 8; ++ct) acc[rt][ct] = (f32x4){0.f, 0.f, 0.f, 0.f};

    union BU { uint u[4]; bf16x8 v; };

    for (int kt = 0; kt < 4; ++kt) {
        int kb = kt * 32 + lg * 8;              // this lane's 8 k's: kb..kb+7
        // B frags for 8 col-tiles: WX[kb+j][ct*16 + lrow]
        BU B[8];
#pragma unroll
        for (int ct = 0; ct < 8; ++ct) {
            float b0 = WX[(size_t)(kb + 0) * 128 + ct * 16 + lrow];
            float b1 = WX[(size_t)(kb + 1) * 128 + ct * 16 + lrow];
            float b2 = WX[(size_t)(kb + 2) * 128 + ct * 16 + lrow];
            float b3 = WX[(size_t)(kb + 3) * 128 + ct * 16 + lrow];
            float b4 = WX[(size_t)(kb + 4) * 128 + ct * 16 + lrow];
            float b5 = WX[(size_t)(kb + 5) * 128 + ct * 16 + lrow];
            float b6 = WX[(size_t)(kb + 6) * 128 + ct * 16 + lrow];
            float b7 = WX[(size_t)(kb + 7) * 128 + ct * 16 + lrow];
            B[ct].u[0] = pack_bf16x2(b0, b1);
            B[ct].u[1] = pack_bf16x2(b2, b3);
            B[ct].u[2] = pack_bf16x2(b4, b5);
            B[ct].u[3] = pack_bf16x2(b6, b7);
        }
#pragma unroll
        for (int rt = 0; rt < 2; ++rt) {
            int ar = r0 + rt * 16 + lrow;
            int arc = ar < N ? ar : N - 1;       // clamp OOB (stores guarded)
            const float* xp = &x[(size_t)arc * 128 + kb];
            float4 a0 = *(const float4*)xp;
            float4 a1 = *(const float4*)(xp + 4);
            BU A;
            A.u[0] = pack_bf16x2(a0.x, a0.y);
            A.u[1] = pack_bf16x2(a0.z, a0.w);
            A.u[2] = pack_bf16x2(a1.x, a1.y);
            A.u[3] = pack_bf16x2(a1.z, a1.w);
#pragma unroll
            for (int ct = 0; ct < 8; ++ct)
                acc[rt][ct] = __builtin_amdgcn_mfma_f32_16x16x32_bf16(
                    A.v, B[ct].v, acc[rt][ct], 0, 0, 0);
        }
    }

    // epilogue: C row = (lane>>4)*4 + reg, col = ct*16 + (lane&15)  [m89 layout]
#pragma unroll
    for (int rt = 0; rt < 2; ++rt) {
#pragma unroll
        for (int r = 0; r < 4; ++r) {
            int srow = r0 + rt * 16 + lg * 4 + r;
            int sc = srow < N ? srow : N - 1;
            float dn = dvec[sc];
            int ai = assign[sc];
            float dca = dcol[ai];
            bool im = (sc < M);
            float drw = im ? RSQRT2 : 1.0f;
            float dci = im ? dcol[sc] : 0.0f;
#pragma unroll
            for (int ct = 0; ct < 8; ++ct) {
                int col = ct * 16 + lrow;
                float bh = dca * ZA[(size_t)ai * 128 + col];
                if (im) bh = fmaf(dci, ZA[(size_t)sc * 128 + col], bh);
                float v = dn * (acc[rt][ct][r] + bh * drw);
                float vpartner = __shfl_xor(v, 1);
                if (((lane & 1) == 0) && srow < N)
                    Gp[(size_t)srow * 64 + ct * 8 + (lrow >> 1)] = pack_bf16x2(v, vpartner);
            }
        }
    }
}

// ---------------- final: out = (d_i*(sum G'_c + G'_i) + Zprime)/3 ----------
// G' has d folded in. One wave per node; lane = dims (2l, 2l+1).

__global__ __launch_bounds__(256) void k_final(
    const uint* __restrict__ Gp, const float* __restrict__ d,
    const int* __restrict__ row_ptr, const int* __restrict__ col_sorted,
    const float* __restrict__ ZW, const float* __restrict__ dcol,
    const int* __restrict__ assign, float* __restrict__ out, int N, int M) {
    int wid = threadIdx.x >> 6;
    int lane = threadIdx.x & 63;
    int i = blockIdx.x * 4 + wid;
    if (i >= N) return;

    int s = row_ptr[i];
    int e = row_ptr[i + 1];
    float ax = 0.f, ay = 0.f;
    int j = s;
    for (; j + 8 <= e; j += 8) {                 // 8 independent load chains
        int c0 = col_sorted[j],     c1 = col_sorted[j + 1];
        int c2 = col_sorted[j + 2], c3 = col_sorted[j + 3];
        int c4 = col_sorted[j + 4], c5 = col_sorted[j + 5];
        int c6 = col_sorted[j + 6], c7 = col_sorted[j + 7];
        uint g0 = Gp[(size_t)c0 * 64 + lane];
        uint g1 = Gp[(size_t)c1 * 64 + lane];
        uint g2 = Gp[(size_t)c2 * 64 + lane];
        uint g3 = Gp[(size_t)c3 * 64 + lane];
        uint g4 = Gp[(size_t)c4 * 64 + lane];
        uint g5 = Gp[(size_t)c5 * 64 + lane];
        uint g6 = Gp[(size_t)c6 * 64 + lane];
        uint g7 = Gp[(size_t)c7 * 64 + lane];
        ax += blo(g0) + blo(g1) + blo(g2) + blo(g3) + blo(g4) + blo(g5) + blo(g6) + blo(g7);
        ay += bhi(g0) + bhi(g1) + bhi(g2) + bhi(g3) + bhi(g4) + bhi(g5) + bhi(g6) + bhi(g7);
    }
    for (; j < e; ++j) {
        uint g = Gp[(size_t)col_sorted[j] * 64 + lane];
        ax += blo(g);
        ay += bhi(g);
    }
    float di = d[i];
    uint gi = Gp[(size_t)i * 64 + lane];
    float ox = di * (ax + blo(gi));
    float oy = di * (ay + bhi(gi));

    int ai = assign[i];
    float dca = dcol[ai];
    const float2* ZW2 = (const float2*)ZW;
    float2 zw = ZW2[ai * 64 + lane];
    float zx = dca * zw.x, zy = dca * zw.y;
    if (i < M) {
        float dci = dcol[i];
        float2 zwi = ZW2[i * 64 + lane];
        zx = fmaf(dci, zwi.x, zx);
        zy = fmaf(dci, zwi.y, zy);
    }
    float dr = (i < M) ? RSQRT2 : 1.0f;

    float2 o;
    o.x = (ox + zx * dr) * (1.0f / 3.0f);
    o.y = (oy + zy * dr) * (1.0f / 3.0f);
    ((float2*)out)[(size_t)i * 64 + lane] = o;
}

// ---------------- launch ----------------

extern "C" void kernel_launch(void* const* d_in, const int* in_sizes, int n_in,
                              void* d_out, int out_size, void* d_ws, size_t ws_size,
                              hipStream_t stream) {
    const float* x      = (const float*)d_in[0];
    const int*   ei     = (const int*)d_in[1];
    const float* bcf    = (const float*)d_in[2];
    const int*   assign = (const int*)d_in[3];
    const float* WX     = (const float*)d_in[4];
    const float* WZ     = (const float*)d_in[5];
    const float* WA     = (const float*)d_in[6];
    float* out = (float*)d_out;

    const int N = in_sizes[0] / 128;
    const int E = in_sizes[1] / 2;
    const int M = in_sizes[2] / 128;
    const int NB = (N + 255) >> 8;      // coarse buckets of 256 rows (<= MAXNB)

    char* p = (char*)d_ws;
    auto alloc = [&](size_t bytes) -> void* {
        void* r = (void*)p;
        p += (bytes + 255) & ~(size_t)255;
        return r;
    };
    int*   coarse_row = (int*)alloc(MAXNB * 4);
    int*   coarse_col = (int*)alloc(MAXNB * 4);
    int*   fill_row   = (int*)alloc(MAXNB * 4);
    int*   fill_col   = (int*)alloc(MAXNB * 4);
    int*   bc_cnt     = (int*)alloc((size_t)M * 4);
    size_t zero_bytes = (size_t)(p - (char*)d_ws);   // atomic counters must start at 0
    int*   row_off    = (int*)alloc((MAXNB + 1) * 4);
    int*   col_off    = (int*)alloc((MAXNB + 1) * 4);
    int*   row_ptr    = (int*)alloc((size_t)(N + 1) * 4);
    float* dvec       = (float*)alloc((size_t)N * 4);
    float* dcol       = (float*)alloc((size_t)M * 4);
    float* ZW         = (float*)alloc((size_t)M * 128 * 4);
    float* ZA         = (float*)alloc((size_t)M * 128 * 4);
    uint*  packed     = (uint*)alloc((size_t)E * 4);
    uchar* colb       = (uchar*)alloc((size_t)E);
    int*   col_sorted = (int*)alloc((size_t)E * 4);
    uint*  Gp         = (uint*)alloc((size_t)N * 64 * 4);   // packed bf16x2 of d*G

    hipMemsetAsync(d_ws, 0, zero_bytes, stream);

    int nbE = (E + EPB - 1) / EPB;
    int nbN = (N + 255) / 256;
    int nbK1 = nbE > nbN ? nbE : nbN;

    k_coarse<<<nbK1, 256, 0, stream>>>(ei, E, assign, N, NB, coarse_row, coarse_col, bc_cnt);
    k_bc_gemm<<<(M + 15) / 16, 128, 0, stream>>>(bcf, WZ, WA, ZW, ZA, M);
    k_scan_small<<<1, 1024, 0, stream>>>(coarse_row, coarse_col, bc_cnt, NB, M, E, N,
                                         row_off, col_off, dcol, row_ptr);
    k_scatter<<<nbE, 256, 0, stream>>>(ei, E, NB, row_off, col_off,
                                       fill_row, fill_col, packed, colb);
    k_fine_row<<<NB, 256, 0, stream>>>(packed, row_off, N, row_ptr, col_sorted);
    k_fine_col<<<NB, 256, 0, stream>>>(colb, col_off, N, dvec);

    k_G<<<(N + 127) / 128, 256, 0, stream>>>(x, WX, ZA, assign, dcol, dvec, Gp, N, M);
    k_final<<<(N + 3) / 4, 256, 0, stream>>>(Gp, dvec, row_ptr, col_sorted, ZW, dcol, assign, out, N, M);
}